// Round 16
// baseline (1609.075 us; speedup 1.0000x reference)
//
#include <hip/hip_runtime.h>
#include <cfloat>
#include <cstdint>
#include <cstddef>

#define N_ROWS 32768
#define K_CODES 8192
#define DIM 512
#define BETA 0.25

typedef unsigned short u16;
typedef _Float16 half8 __attribute__((ext_vector_type(8)));
typedef float f32x4 __attribute__((ext_vector_type(4)));

#define BKH 64        // k-halves per LDS tile
#define OVCAP 512     // per-block LDS overflow buffer entries
#define DELTA_A 0.4f  // append window on scaled dot (bound needs 0.213)

#define GLOAD_LDS16(g, l)                                          \
  __builtin_amdgcn_global_load_lds(                                \
      (const __attribute__((address_space(1))) void*)(g),          \
      (__attribute__((address_space(3))) void*)(l), 16, 0, 0)

__device__ inline u16 f2h(float x) {
  union { _Float16 h; u16 u; } c;
  c.h = (_Float16)x;
  return c.u;
}

// order-preserving float<->uint encoding (monotone): enc(a)<enc(b) iff a<b.
// enc(finite) != 0, so key 0 serves as "-inf / unset".
__device__ inline unsigned fenc(float f) {
  unsigned u = __float_as_uint(f);
  return (u & 0x80000000u) ? ~u : (u | 0x80000000u);
}
__device__ inline float fdec(unsigned k) {
  return (k & 0x80000000u) ? __uint_as_float(k & 0x7fffffffu)
                           : __uint_as_float(~k);
}

// ---------------- cvt: f32 -> f16 (optionally scaled), 8 elems/thread ----------------
// Also resets ovcnt and the rowhint array (z-pass only).
__global__ __launch_bounds__(256)
void vq_cvt(const float* __restrict__ src, u16* __restrict__ dst, float scale,
            int n8, int* ovcnt_reset, unsigned* __restrict__ rowhint_init) {
  if (ovcnt_reset != nullptr && blockIdx.x == 0 && threadIdx.x == 0) *ovcnt_reset = 0;
  int i = blockIdx.x * 256 + threadIdx.x;
  if (rowhint_init != nullptr && i < N_ROWS) rowhint_init[i] = 0u;
  if (i >= n8) return;
  float4 a = ((const float4*)src)[(size_t)i * 2];
  float4 b = ((const float4*)src)[(size_t)i * 2 + 1];
  uint4 o;
  o.x = (unsigned)f2h(a.x * scale) | ((unsigned)f2h(a.y * scale) << 16);
  o.y = (unsigned)f2h(a.z * scale) | ((unsigned)f2h(a.w * scale) << 16);
  o.z = (unsigned)f2h(b.x * scale) | ((unsigned)f2h(b.y * scale) << 16);
  o.w = (unsigned)f2h(b.z * scale) | ((unsigned)f2h(b.w * scale) << 16);
  ((uint4*)dst)[i] = o;
}

// ---------------- s1: numpy-exact fp32 pairwise sum of z*z (float4 loads) ------------
// Arithmetic chain bit-identical to the r2-validated version; only loads vectorized.
__global__ __launch_bounds__(256)
void vq_s1(const float* __restrict__ z, float* __restrict__ s1out) {
  int row = blockIdx.x * 256 + threadIdx.x;
  const float* p = z + (size_t)row * DIM;
  float lf[4];
#pragma unroll
  for (int L = 0; L < 4; ++L) {
    const float* q = p + L * 128;
    float4 a = *(const float4*)q;
    float4 b = *(const float4*)(q + 4);
    float r[8];
    r[0] = __fmul_rn(a.x, a.x); r[1] = __fmul_rn(a.y, a.y);
    r[2] = __fmul_rn(a.z, a.z); r[3] = __fmul_rn(a.w, a.w);
    r[4] = __fmul_rn(b.x, b.x); r[5] = __fmul_rn(b.y, b.y);
    r[6] = __fmul_rn(b.z, b.z); r[7] = __fmul_rn(b.w, b.w);
#pragma unroll
    for (int i = 8; i < 128; i += 8) {
      float4 c = *(const float4*)(q + i);
      float4 d = *(const float4*)(q + i + 4);
      r[0] = __fadd_rn(r[0], __fmul_rn(c.x, c.x));
      r[1] = __fadd_rn(r[1], __fmul_rn(c.y, c.y));
      r[2] = __fadd_rn(r[2], __fmul_rn(c.z, c.z));
      r[3] = __fadd_rn(r[3], __fmul_rn(c.w, c.w));
      r[4] = __fadd_rn(r[4], __fmul_rn(d.x, d.x));
      r[5] = __fadd_rn(r[5], __fmul_rn(d.y, d.y));
      r[6] = __fadd_rn(r[6], __fmul_rn(d.z, d.z));
      r[7] = __fadd_rn(r[7], __fmul_rn(d.w, d.w));
    }
    float s01 = __fadd_rn(r[0], r[1]);
    float s23 = __fadd_rn(r[2], r[3]);
    float s45 = __fadd_rn(r[4], r[5]);
    float s67 = __fadd_rn(r[6], r[7]);
    lf[L] = __fadd_rn(__fadd_rn(s01, s23), __fadd_rn(s45, s67));
  }
  s1out[row] = __fadd_rn(__fadd_rn(lf[0], lf[1]), __fadd_rn(lf[2], lf[3]));
}

// ---------------- gemm: r12-validated (m97 structure, 3 blocks/CU) + rowhint prune ---
__global__ __launch_bounds__(256, 3)
void vq_gemm(const u16* __restrict__ zh, const u16* __restrict__ ch,
             float* __restrict__ tilemax, uint2* __restrict__ ovlist,
             int* __restrict__ ovcnt, int gcap, unsigned* __restrict__ rowhint) {
  __shared__ u16 Ah[128 * BKH];
  __shared__ u16 Bh[128 * BKH];
  __shared__ float rmaxw[2][128];
  __shared__ uint2 obuf[OVCAP];
  __shared__ int ocnt, gbase;
  const int tid = threadIdx.x;
  const int lane = tid & 63;
  const int wid = tid >> 6;
  const int col0 = blockIdx.x * 128;
  const int row0 = blockIdx.y * 128;
  const int wr = (wid >> 1) * 64;  // wave row offset in tile
  const int wc = (wid & 1) * 64;   // wave col offset in tile
  if (tid == 0) ocnt = 0;

  f32x4 acc[4][4];
#pragma unroll
  for (int m = 0; m < 4; ++m)
#pragma unroll
    for (int n = 0; n < 4; ++n) acc[m][n] = (f32x4){0.f, 0.f, 0.f, 0.f};

  // staging: 16 gload_lds per matrix (1KB each), 4 per wave. phys LDS byte
  // p = (wid*4+j)*1024 + lane*16; row = p>>7; source pre-swizzled (rule #21).
  const u16* baseA = zh + (size_t)row0 * DIM;
  const u16* baseB = ch + (size_t)col0 * DIM;
  unsigned offs[4], lofs[4];
#pragma unroll
  for (int jj = 0; jj < 4; ++jj) {
    int p = (wid * 4 + jj) * 1024 + lane * 16;
    int row = p >> 7;
    int ninner = (p & 127) ^ ((row & 7) << 4);
    offs[jj] = (unsigned)(row * DIM + (ninner >> 1));
    lofs[jj] = (wid * 4 + jj) * 512;  // halves
  }

  // ds_read byte offsets (swizzled), constant across K-tiles
  int pbA[4][2], pbB[4][2];
#pragma unroll
  for (int m = 0; m < 4; ++m) {
#pragma unroll
    for (int k2 = 0; k2 < 2; ++k2) {
      int khalf = k2 * 32 + (lane >> 4) * 8;
      int R = wr + m * 16 + (lane & 15);
      pbA[m][k2] = (R * 128 + khalf * 2) ^ ((R & 7) << 4);
      int C = wc + m * 16 + (lane & 15);
      pbB[m][k2] = (C * 128 + khalf * 2) ^ ((C & 7) << 4);
    }
  }

  for (int t = 0; t < DIM / BKH; ++t) {
    __syncthreads();  // previous tile's reads done
#pragma unroll
    for (int jj = 0; jj < 4; ++jj) {
      GLOAD_LDS16(baseA + offs[jj] + t * BKH, Ah + lofs[jj]);
      GLOAD_LDS16(baseB + offs[jj] + t * BKH, Bh + lofs[jj]);
    }
    __syncthreads();  // compiler drains vmcnt before barrier
#pragma unroll
    for (int k2 = 0; k2 < 2; ++k2) {
      half8 af[4], bf[4];
#pragma unroll
      for (int m = 0; m < 4; ++m)
        af[m] = *(const half8*)((const char*)Ah + pbA[m][k2]);
#pragma unroll
      for (int n = 0; n < 4; ++n)
        bf[n] = *(const half8*)((const char*)Bh + pbB[n][k2]);
#pragma unroll
      for (int m = 0; m < 4; ++m)
#pragma unroll
        for (int n = 0; n < 4; ++n)
          acc[m][n] = __builtin_amdgcn_mfma_f32_16x16x32_f16(af[m], bf[n],
                                                             acc[m][n], 0, 0, 0);
    }
  }

  // epilogue pass 1: per-row max over this wave's 64 cols -> LDS
#pragma unroll
  for (int m = 0; m < 4; ++m) {
#pragma unroll
    for (int rg = 0; rg < 4; ++rg) {
      float mx = acc[m][0][rg];
#pragma unroll
      for (int n = 1; n < 4; ++n) mx = fmaxf(mx, acc[m][n][rg]);
#pragma unroll
      for (int s = 1; s <= 8; s <<= 1) mx = fmaxf(mx, __shfl_xor(mx, s, 64));
      int Rloc = wr + m * 16 + (lane >> 4) * 4 + rg;
      if ((lane & 15) == 0) rmaxw[wid & 1][Rloc] = mx;
    }
  }
  __syncthreads();
  // epilogue pass 2: tile max -> tilemax + rowhint atomicMax; prune appends with
  // thr = max(tile_gm, hint) - DELTA_A. hint <= global row max (monotone), so
  // thr <= gmax - 0.4 always -> candidate set still covers all v >= gmax - 0.213.
#pragma unroll
  for (int m = 0; m < 4; ++m) {
#pragma unroll
    for (int rg = 0; rg < 4; ++rg) {
      int Rloc = wr + m * 16 + (lane >> 4) * 4 + rg;
      int grow = row0 + Rloc;
      float gm = fmaxf(rmaxw[0][Rloc], rmaxw[1][Rloc]);
      if ((wid & 1) == 0 && (lane & 15) == 0) {
        tilemax[(size_t)blockIdx.x * N_ROWS + grow] = gm;
        atomicMax(&rowhint[grow], fenc(gm));
      }
      unsigned hk = rowhint[grow];  // stale-safe (any stale value <= true max)
      float h = hk ? fdec(hk) : -1e30f;
      float thr = fmaxf(gm, h) - DELTA_A;
#pragma unroll
      for (int n = 0; n < 4; ++n) {
        float v = acc[m][n][rg];
        if (v >= thr) {
          int code = col0 + wc + n * 16 + (lane & 15);
          uint2 e = make_uint2(((unsigned)grow << 13) | (unsigned)code,
                               __float_as_uint(v));
          int p = atomicAdd(&ocnt, 1);
          if (p < OVCAP) obuf[p] = e;
          else {
            int g = atomicAdd(ovcnt, 1);
            if (g < gcap) ovlist[g] = e;
          }
        }
      }
    }
  }
  __syncthreads();
  int n = ocnt < OVCAP ? ocnt : OVCAP;
  if (tid == 0) gbase = atomicAdd(ovcnt, n);
  __syncthreads();
  for (int i = tid; i < n; i += 256) {
    int g = gbase + i;
    if (g < gcap) ovlist[g] = obuf[i];
  }
}

// ---------------- merge: per-row global max (8 ILP chains) -> mthr; init win --------
__global__ __launch_bounds__(256)
void vq_merge(const float* __restrict__ tilemax, float* __restrict__ mthr,
              unsigned long long* __restrict__ win) {
  int row = blockIdx.x * 256 + threadIdx.x;
  float g[8];
#pragma unroll
  for (int t = 0; t < 8; ++t) g[t] = tilemax[(size_t)t * N_ROWS + row];
#pragma unroll
  for (int tt = 1; tt < 8; ++tt)
#pragma unroll
    for (int t = 0; t < 8; ++t)
      g[t] = fmaxf(g[t], tilemax[(size_t)(tt * 8 + t) * N_ROWS + row]);
  float gg = fmaxf(fmaxf(fmaxf(g[0], g[1]), fmaxf(g[2], g[3])),
                   fmaxf(fmaxf(g[4], g[5]), fmaxf(g[6], g[7])));
  mthr[row] = gg - DELTA_A;
  win[row] = ~0ULL;
}

__global__ __launch_bounds__(256)
void vq_init(unsigned long long* __restrict__ win) {
  int row = blockIdx.x * 256 + threadIdx.x;
  win[row] = ~0ULL;
}

// ---------------- overflow: filter + exact fp32 chain re-rank ----------------
__global__ __launch_bounds__(256)
void vq_overflow(const float* __restrict__ z, const float* __restrict__ cb,
                 const float* __restrict__ s1, const float* __restrict__ mthr,
                 const uint2* __restrict__ ovlist, const int* __restrict__ ovcnt,
                 int gcap, unsigned long long* __restrict__ win) {
  int n = *ovcnt;
  if (n > gcap) n = gcap;
  for (int i = blockIdx.x * 256 + threadIdx.x; i < n; i += gridDim.x * 256) {
    uint2 e = ovlist[i];
    int row = e.x >> 13;
    int code = e.x & 8191;
    if (__uint_as_float(e.y) < mthr[row]) continue;
    const float* zp = z + (size_t)row * DIM;
    const float* cp = cb + (size_t)code * DIM;
    float acc = 0.f;
    for (int k = 0; k < DIM; k += 4) {
      float4 zv = *(const float4*)(zp + k);
      float4 cv = *(const float4*)(cp + k);
      acc = fmaf(zv.x, cv.x, acc);
      acc = fmaf(zv.y, cv.y, acc);
      acc = fmaf(zv.z, cv.z, acc);
      acc = fmaf(zv.w, cv.w, acc);
    }
    float dq = __fsub_rn(s1[row], __fmul_rn(2.0f, acc));
    unsigned long long key =
        ((unsigned long long)__float_as_uint(dq) << 32) | (unsigned)code;
    atomicMin(&win[row], key);
  }
}

// ---------------- fallback: gated full exact scan (overflow safety) ----------------
__global__ __launch_bounds__(256)
void vq_fallback(const float* __restrict__ z, const float* __restrict__ cb,
                 const float* __restrict__ s1, const int* __restrict__ ovcnt,
                 int gcap, int force, unsigned long long* __restrict__ win) {
  if (!force && *ovcnt <= gcap) return;
  __shared__ float zrow[DIM];
  __shared__ unsigned long long red[256];
  for (int row = blockIdx.x; row < N_ROWS; row += gridDim.x) {
    __syncthreads();
    for (int t = threadIdx.x; t < DIM; t += 256) zrow[t] = z[(size_t)row * DIM + t];
    __syncthreads();
    float s1v = s1[row];
    unsigned long long best = ~0ULL;
    for (int j = threadIdx.x; j < K_CODES; j += 256) {
      const float* cp = cb + (size_t)j * DIM;
      float acc = 0.f;
      for (int k = 0; k < DIM; ++k) acc = fmaf(zrow[k], cp[k], acc);
      float dq = __fsub_rn(s1v, __fmul_rn(2.0f, acc));
      unsigned long long key =
          ((unsigned long long)__float_as_uint(dq) << 32) | (unsigned)j;
      if (key < best) best = key;
    }
    red[threadIdx.x] = best;
    __syncthreads();
    for (int s = 128; s > 0; s >>= 1) {
      if (threadIdx.x < s && red[threadIdx.x + s] < red[threadIdx.x])
        red[threadIdx.x] = red[threadIdx.x + s];
      __syncthreads();
    }
    if (threadIdx.x == 0) atomicMin(&win[row], red[0]);
    __syncthreads();
  }
}

// ---------------- out: gather z_q, write indices, per-row loss (f64) ----------------
__global__ __launch_bounds__(256)
void vq_out(const float* __restrict__ z, const float* __restrict__ cb,
            const unsigned long long* __restrict__ win, float* __restrict__ out,
            double* __restrict__ loss64) {
  int wid = threadIdx.x >> 6, lane = threadIdx.x & 63;
  int row = blockIdx.x * 4 + wid;
  int I1 = (int)(win[row] & 8191ULL);
  const float* zp = z + (size_t)row * DIM + lane * 8;
  const float* cp = cb + (size_t)I1 * DIM + lane * 8;
  float4 z0 = *(const float4*)zp, z1 = *(const float4*)(zp + 4);
  float4 c0 = *(const float4*)cp, c1 = *(const float4*)(cp + 4);
  *(float4*)&out[(size_t)row * DIM + lane * 8] = c0;
  *(float4*)&out[(size_t)row * DIM + lane * 8 + 4] = c1;
  double s = 0.0, d;
  d = (double)z0.x - c0.x; s += d * d;
  d = (double)z0.y - c0.y; s += d * d;
  d = (double)z0.z - c0.z; s += d * d;
  d = (double)z0.w - c0.w; s += d * d;
  d = (double)z1.x - c1.x; s += d * d;
  d = (double)z1.y - c1.y; s += d * d;
  d = (double)z1.z - c1.z; s += d * d;
  d = (double)z1.w - c1.w; s += d * d;
#pragma unroll
  for (int m = 32; m >= 1; m >>= 1) s += __shfl_down(s, m, 64);
  if (lane == 0) {
    loss64[row] = s;
    out[(size_t)N_ROWS * DIM + row] = (float)I1;
  }
}

// ---------------- loss: deterministic reduction ----------------
__global__ __launch_bounds__(1024)
void vq_loss(const double* __restrict__ loss64, float* __restrict__ out) {
  __shared__ double sd[1024];
  double s = 0.0;
  for (int i = threadIdx.x; i < N_ROWS; i += 1024) s += loss64[i];
  sd[threadIdx.x] = s;
  __syncthreads();
  for (int k = 512; k > 0; k >>= 1) {
    if (threadIdx.x < k) sd[threadIdx.x] += sd[threadIdx.x + k];
    __syncthreads();
  }
  if (threadIdx.x == 0)
    out[(size_t)N_ROWS * DIM + N_ROWS] =
        (float)(BETA * sd[0] / ((double)N_ROWS * (double)DIM));
}

extern "C" void kernel_launch(void* const* d_in, const int* in_sizes, int n_in,
                              void* d_out, int out_size, void* d_ws, size_t ws_size,
                              hipStream_t stream) {
  const float* z = (const float*)d_in[0];
  const float* cb = (const float*)d_in[1];
  float* out = (float*)d_out;
  char* ws = (char*)d_ws;

  // fast-path ws layout
  const size_t OFF_ZH = 0;                         // 33,554,432
  const size_t OFF_CH = 33554432;                  //  8,388,608
  const size_t OFF_S1 = 41943040;                  //    131,072
  const size_t OFF_MT = 42074112;                  //    131,072
  const size_t OFF_WIN = 42205184;                 //    262,144
  const size_t OFF_L64 = 42467328;                 //    262,144
  const size_t OFF_TM = 42729472;                  //  8,388,608
  const size_t OFF_OC = 51118080;                  //         16
  const size_t OFF_RH = 51118096;                  //    131,072 (rowhint)
  const size_t OFF_OV = 51249168;                  // list...
  const size_t MIN_FAST = OFF_OV + (size_t)8 * 1024 * 1024;

  if (ws_size >= MIN_FAST) {
    u16* zh = (u16*)(ws + OFF_ZH);
    u16* ch = (u16*)(ws + OFF_CH);
    float* s1f = (float*)(ws + OFF_S1);
    float* mthr = (float*)(ws + OFF_MT);
    unsigned long long* win = (unsigned long long*)(ws + OFF_WIN);
    double* loss64 = (double*)(ws + OFF_L64);
    float* tilemax = (float*)(ws + OFF_TM);
    int* ovcnt = (int*)(ws + OFF_OC);
    unsigned* rowhint = (unsigned*)(ws + OFF_RH);
    uint2* ovlist = (uint2*)(ws + OFF_OV);
    long long gc = (long long)(ws_size - OFF_OV) / 8;
    if (gc > 6 * 1024 * 1024) gc = 6 * 1024 * 1024;
    int gcap = (int)gc;

    vq_cvt<<<N_ROWS * DIM / 8 / 256, 256, 0, stream>>>(z, zh, 1.0f,
                                                       N_ROWS * DIM / 8, ovcnt,
                                                       rowhint);
    vq_cvt<<<K_CODES * DIM / 8 / 256, 256, 0, stream>>>(cb, ch, 4096.0f,
                                                        K_CODES * DIM / 8, nullptr,
                                                        nullptr);
    vq_s1<<<N_ROWS / 256, 256, 0, stream>>>(z, s1f);
    vq_gemm<<<dim3(K_CODES / 128, N_ROWS / 128), 256, 0, stream>>>(
        zh, ch, tilemax, ovlist, ovcnt, gcap, rowhint);
    vq_merge<<<N_ROWS / 256, 256, 0, stream>>>(tilemax, mthr, win);
    vq_overflow<<<2048, 256, 0, stream>>>(z, cb, s1f, mthr, ovlist, ovcnt, gcap, win);
    vq_fallback<<<2048, 256, 0, stream>>>(z, cb, s1f, ovcnt, gcap, 0, win);
    vq_out<<<N_ROWS / 4, 256, 0, stream>>>(z, cb, win, out, loss64);
    vq_loss<<<1, 1024, 0, stream>>>(loss64, out);
  } else {
    // tiny-ws safe path: exact full scan
    float* s1f = (float*)(ws + 0);                                 // 131,072
    unsigned long long* win = (unsigned long long*)(ws + 131072);  // 262,144
    double* loss64 = (double*)(ws + 393216);                       // 262,144
    vq_s1<<<N_ROWS / 256, 256, 0, stream>>>(z, s1f);
    vq_init<<<N_ROWS / 256, 256, 0, stream>>>(win);
    vq_fallback<<<2048, 256, 0, stream>>>(z, cb, s1f, nullptr, 0, 1, win);
    vq_out<<<N_ROWS / 4, 256, 0, stream>>>(z, cb, win, out, loss64);
    vq_loss<<<1, 1024, 0, stream>>>(loss64, out);
  }
}

// Round 17
// 677.860 us; speedup vs baseline: 2.3738x; 2.3738x over previous
//
#include <hip/hip_runtime.h>
#include <cfloat>
#include <cstdint>
#include <cstddef>

#define N_ROWS 32768
#define K_CODES 8192
#define DIM 512
#define BETA 0.25

typedef unsigned short u16;
typedef _Float16 half8 __attribute__((ext_vector_type(8)));
typedef float f32x4 __attribute__((ext_vector_type(4)));

#define BM 256           // block rows (z)
#define BN 256           // block cols (codes)
#define SKH 32           // k-halves per ring sub-tile
#define NPH (DIM / SKH)  // 16 phases
#define OVCAP 512        // per-block LDS overflow buffer entries
#define DELTA_A 0.4f     // append window on scaled dot (bound needs 0.213)

#define GLOAD_LDS16(g, l)                                          \
  __builtin_amdgcn_global_load_lds(                                \
      (const __attribute__((address_space(1))) void*)(g),          \
      (__attribute__((address_space(3))) void*)(l), 16, 0, 0)

__device__ inline u16 f2h(float x) {
  union { _Float16 h; u16 u; } c;
  c.h = (_Float16)x;
  return c.u;
}

// ---------------- cvt: f32 -> f16 (optionally scaled), 8 elems/thread ----------------
__global__ __launch_bounds__(256)
void vq_cvt(const float* __restrict__ src, u16* __restrict__ dst, float scale,
            int n8, int* ovcnt_reset) {
  if (ovcnt_reset != nullptr && blockIdx.x == 0 && threadIdx.x == 0) *ovcnt_reset = 0;
  int i = blockIdx.x * 256 + threadIdx.x;
  if (i >= n8) return;
  float4 a = ((const float4*)src)[(size_t)i * 2];
  float4 b = ((const float4*)src)[(size_t)i * 2 + 1];
  uint4 o;
  o.x = (unsigned)f2h(a.x * scale) | ((unsigned)f2h(a.y * scale) << 16);
  o.y = (unsigned)f2h(a.z * scale) | ((unsigned)f2h(a.w * scale) << 16);
  o.z = (unsigned)f2h(b.x * scale) | ((unsigned)f2h(b.y * scale) << 16);
  o.w = (unsigned)f2h(b.z * scale) | ((unsigned)f2h(b.w * scale) << 16);
  ((uint4*)dst)[i] = o;
}

// ---------------- s1: numpy-exact fp32 pairwise sum of z*z (float4 loads; r16-ok) ----
__global__ __launch_bounds__(256)
void vq_s1(const float* __restrict__ z, float* __restrict__ s1out) {
  int row = blockIdx.x * 256 + threadIdx.x;
  const float* p = z + (size_t)row * DIM;
  float lf[4];
#pragma unroll
  for (int L = 0; L < 4; ++L) {
    const float* q = p + L * 128;
    float4 a = *(const float4*)q;
    float4 b = *(const float4*)(q + 4);
    float r[8];
    r[0] = __fmul_rn(a.x, a.x); r[1] = __fmul_rn(a.y, a.y);
    r[2] = __fmul_rn(a.z, a.z); r[3] = __fmul_rn(a.w, a.w);
    r[4] = __fmul_rn(b.x, b.x); r[5] = __fmul_rn(b.y, b.y);
    r[6] = __fmul_rn(b.z, b.z); r[7] = __fmul_rn(b.w, b.w);
#pragma unroll
    for (int i = 8; i < 128; i += 8) {
      float4 c = *(const float4*)(q + i);
      float4 d = *(const float4*)(q + i + 4);
      r[0] = __fadd_rn(r[0], __fmul_rn(c.x, c.x));
      r[1] = __fadd_rn(r[1], __fmul_rn(c.y, c.y));
      r[2] = __fadd_rn(r[2], __fmul_rn(c.z, c.z));
      r[3] = __fadd_rn(r[3], __fmul_rn(c.w, c.w));
      r[4] = __fadd_rn(r[4], __fmul_rn(d.x, d.x));
      r[5] = __fadd_rn(r[5], __fmul_rn(d.y, d.y));
      r[6] = __fadd_rn(r[6], __fmul_rn(d.z, d.z));
      r[7] = __fadd_rn(r[7], __fmul_rn(d.w, d.w));
    }
    float s01 = __fadd_rn(r[0], r[1]);
    float s23 = __fadd_rn(r[2], r[3]);
    float s45 = __fadd_rn(r[4], r[5]);
    float s67 = __fadd_rn(r[6], r[7]);
    lf[L] = __fadd_rn(__fadd_rn(s01, s23), __fadd_rn(s45, s67));
  }
  s1out[row] = __fadd_rn(__fadd_rn(lf[0], lf[1]), __fadd_rn(lf[2], lf[3]));
}

// ---------------- gemm: r10-validated 256x256 counted-vmcnt ring + XCD L2 tiling -----
// (best-total configuration measured: 491 µs gemm, 14 MB WRITE, 0 conflicts)
__global__ __launch_bounds__(512, 2)
void vq_gemm(const u16* __restrict__ zh, const u16* __restrict__ ch,
             float* __restrict__ tilemax, uint2* __restrict__ ovlist,
             int* __restrict__ ovcnt, int gcap) {
  __shared__ u16 ring[4][16384];  // per slot: A 8192 halves | B 8192 halves
  __shared__ float rmaxw[4][BM];
  __shared__ uint2 obuf[OVCAP];
  __shared__ int ocnt, gbase;
  const int tid = threadIdx.x;
  const int lane = tid & 63;
  const int wid = tid >> 6;  // 0..7
  const int wrow = (wid >> 2) * 128;
  const int wcol = (wid & 3) * 64;
  // XCD-aware swizzle: xcd = wg&7 owns colblocks 4*xcd..4*xcd+3; col-inner sweep.
  const int wg = blockIdx.x;
  const int xcd = wg & 7;
  const int kk = wg >> 3;               // 0..511
  const int colb = xcd * 4 + (kk & 3);  // 0..31
  const int rowb = kk >> 2;             // 0..127
  const int col0 = colb * BN;
  const int row0 = rowb * BM;
  if (tid == 0) ocnt = 0;

  f32x4 acc[8][4];
#pragma unroll
  for (int m = 0; m < 8; ++m)
#pragma unroll
    for (int n = 0; n < 4; ++n) acc[m][n] = (f32x4){0.f, 0.f, 0.f, 0.f};

  // stage addressing (linear LDS dest, pre-swizzled global source; rule #21)
  const int arow = tid >> 2;  // 0..127
  const int sslot8 = (((tid & 3) ^ ((tid >> 3) & 3))) * 8;
  const u16* pa0 = zh + (size_t)(row0 + arow) * DIM + sslot8;
  const u16* pa1 = pa0 + (size_t)128 * DIM;
  const u16* pb0 = ch + (size_t)(col0 + arow) * DIM + sslot8;
  const u16* pb1 = pb0 + (size_t)128 * DIM;
  const unsigned dof = tid * 8;  // halves

#define STAGE(s)                                              \
  {                                                           \
    u16* sl_ = ring[(s) & 3];                                 \
    GLOAD_LDS16(pa0 + (s) * SKH, sl_ + dof);                  \
    GLOAD_LDS16(pa1 + (s) * SKH, sl_ + 4096 + dof);           \
    GLOAD_LDS16(pb0 + (s) * SKH, sl_ + 8192 + dof);           \
    GLOAD_LDS16(pb1 + (s) * SKH, sl_ + 12288 + dof);          \
  }

  // ds_read byte offsets (swizzled; validated 0-conflict pattern)
  const int xorv = ((lane >> 4) ^ ((lane >> 1) & 3)) << 4;
  const int aoff = (wrow + (lane & 15)) * 64 + xorv;           // + m*1024
  const int boff = 16384 + (wcol + (lane & 15)) * 64 + xorv;   // + n*1024

  // prologue: stage sub-tiles 0 and 1 (8 loads in flight)
  STAGE(0);
  STAGE(1);

#pragma unroll
  for (int s = 0; s < NPH; ++s) {
    // 1. issue next prefetch (distance 2)
    if (s + 2 < NPH) STAGE(s + 2);
    // 2. counted wait: own sub-tile-s loads complete (8 newer may stay in flight)
    if (s < NPH - 2) {
      asm volatile("s_waitcnt vmcnt(8)" ::: "memory");
    } else if (s == NPH - 2) {
      asm volatile("s_waitcnt vmcnt(4)" ::: "memory");
    } else {
      asm volatile("s_waitcnt vmcnt(0)" ::: "memory");
    }
    __builtin_amdgcn_sched_barrier(0);
    // 3. all waves' sub-tile-s loads landed
    __builtin_amdgcn_s_barrier();
    // 4. fragment reads for this sub-tile
    const char* sl = (const char*)ring[s & 3];
    half8 af[8], bf[4];
#pragma unroll
    for (int m = 0; m < 8; ++m)
      af[m] = *(const half8*)(sl + aoff + m * 1024);
#pragma unroll
    for (int n = 0; n < 4; ++n)
      bf[n] = *(const half8*)(sl + boff + n * 1024);
    // 5. drain LDS reads; fence the scheduler (rule #18)
    asm volatile("s_waitcnt lgkmcnt(0)" ::: "memory");
    __builtin_amdgcn_sched_barrier(0);
    // 6. MFMA cluster (T5)
    __builtin_amdgcn_s_setprio(1);
#pragma unroll
    for (int m = 0; m < 8; ++m)
#pragma unroll
      for (int n = 0; n < 4; ++n)
        acc[m][n] = __builtin_amdgcn_mfma_f32_16x16x32_f16(af[m], bf[n],
                                                           acc[m][n], 0, 0, 0);
    __builtin_amdgcn_s_setprio(0);
  }
#undef STAGE

  // epilogue pass 1: per-row max over this wave's 64 cols -> rmaxw[wn]
  const int wn = wid & 3;
#pragma unroll
  for (int m = 0; m < 8; ++m) {
#pragma unroll
    for (int rg = 0; rg < 4; ++rg) {
      float mx = acc[m][0][rg];
#pragma unroll
      for (int n = 1; n < 4; ++n) mx = fmaxf(mx, acc[m][n][rg]);
#pragma unroll
      for (int s = 1; s <= 8; s <<= 1) mx = fmaxf(mx, __shfl_xor(mx, s, 64));
      int Rloc = wrow + m * 16 + (lane >> 4) * 4 + rg;
      if ((lane & 15) == 0) rmaxw[wn][Rloc] = mx;
    }
  }
  __syncthreads();
  // epilogue pass 2: combined 256-col tile max -> tilemax + threshold append (LDS buf)
#pragma unroll
  for (int m = 0; m < 8; ++m) {
#pragma unroll
    for (int rg = 0; rg < 4; ++rg) {
      int Rloc = wrow + m * 16 + (lane >> 4) * 4 + rg;
      int grow = row0 + Rloc;
      float gm = fmaxf(fmaxf(rmaxw[0][Rloc], rmaxw[1][Rloc]),
                       fmaxf(rmaxw[2][Rloc], rmaxw[3][Rloc]));
      if (wn == 0 && (lane & 15) == 0)
        tilemax[(size_t)colb * N_ROWS + grow] = gm;
      float thr = gm - DELTA_A;
#pragma unroll
      for (int n = 0; n < 4; ++n) {
        float v = acc[m][n][rg];
        if (v >= thr) {
          int code = col0 + wcol + n * 16 + (lane & 15);
          uint2 e = make_uint2(((unsigned)grow << 13) | (unsigned)code,
                               __float_as_uint(v));
          int p = atomicAdd(&ocnt, 1);
          if (p < OVCAP) obuf[p] = e;
          else {
            int g = atomicAdd(ovcnt, 1);
            if (g < gcap) ovlist[g] = e;
          }
        }
      }
    }
  }
  __syncthreads();
  int n = ocnt < OVCAP ? ocnt : OVCAP;
  if (tid == 0) gbase = atomicAdd(ovcnt, n);
  __syncthreads();
  for (int i = tid; i < n; i += 512) {
    int g = gbase + i;
    if (g < gcap) ovlist[g] = obuf[i];
  }
}

// ---------------- merge: per-row global max (8 ILP chains over 32 tiles) ------------
__global__ __launch_bounds__(256)
void vq_merge(const float* __restrict__ tilemax, float* __restrict__ mthr,
              unsigned long long* __restrict__ win) {
  int row = blockIdx.x * 256 + threadIdx.x;
  float g[8];
#pragma unroll
  for (int t = 0; t < 8; ++t) g[t] = tilemax[(size_t)t * N_ROWS + row];
#pragma unroll
  for (int tt = 1; tt < 4; ++tt)
#pragma unroll
    for (int t = 0; t < 8; ++t)
      g[t] = fmaxf(g[t], tilemax[(size_t)(tt * 8 + t) * N_ROWS + row]);
  float gg = fmaxf(fmaxf(fmaxf(g[0], g[1]), fmaxf(g[2], g[3])),
                   fmaxf(fmaxf(g[4], g[5]), fmaxf(g[6], g[7])));
  mthr[row] = gg - DELTA_A;
  win[row] = ~0ULL;
}

__global__ __launch_bounds__(256)
void vq_init(unsigned long long* __restrict__ win) {
  int row = blockIdx.x * 256 + threadIdx.x;
  win[row] = ~0ULL;
}

// ---------------- overflow: filter + exact fp32 chain re-rank ----------------
__global__ __launch_bounds__(256)
void vq_overflow(const float* __restrict__ z, const float* __restrict__ cb,
                 const float* __restrict__ s1, const float* __restrict__ mthr,
                 const uint2* __restrict__ ovlist, const int* __restrict__ ovcnt,
                 int gcap, unsigned long long* __restrict__ win) {
  int n = *ovcnt;
  if (n > gcap) n = gcap;
  for (int i = blockIdx.x * 256 + threadIdx.x; i < n; i += gridDim.x * 256) {
    uint2 e = ovlist[i];
    int row = e.x >> 13;
    int code = e.x & 8191;
    if (__uint_as_float(e.y) < mthr[row]) continue;
    const float* zp = z + (size_t)row * DIM;
    const float* cp = cb + (size_t)code * DIM;
    float acc = 0.f;
    for (int k = 0; k < DIM; k += 4) {
      float4 zv = *(const float4*)(zp + k);
      float4 cv = *(const float4*)(cp + k);
      acc = fmaf(zv.x, cv.x, acc);
      acc = fmaf(zv.y, cv.y, acc);
      acc = fmaf(zv.z, cv.z, acc);
      acc = fmaf(zv.w, cv.w, acc);
    }
    float dq = __fsub_rn(s1[row], __fmul_rn(2.0f, acc));
    unsigned long long key =
        ((unsigned long long)__float_as_uint(dq) << 32) | (unsigned)code;
    atomicMin(&win[row], key);
  }
}

// ---------------- fallback: gated full exact scan (overflow safety) ----------------
__global__ __launch_bounds__(256)
void vq_fallback(const float* __restrict__ z, const float* __restrict__ cb,
                 const float* __restrict__ s1, const int* __restrict__ ovcnt,
                 int gcap, int force, unsigned long long* __restrict__ win) {
  if (!force && *ovcnt <= gcap) return;
  __shared__ float zrow[DIM];
  __shared__ unsigned long long red[256];
  for (int row = blockIdx.x; row < N_ROWS; row += gridDim.x) {
    __syncthreads();
    for (int t = threadIdx.x; t < DIM; t += 256) zrow[t] = z[(size_t)row * DIM + t];
    __syncthreads();
    float s1v = s1[row];
    unsigned long long best = ~0ULL;
    for (int j = threadIdx.x; j < K_CODES; j += 256) {
      const float* cp = cb + (size_t)j * DIM;
      float acc = 0.f;
      for (int k = 0; k < DIM; ++k) acc = fmaf(zrow[k], cp[k], acc);
      float dq = __fsub_rn(s1v, __fmul_rn(2.0f, acc));
      unsigned long long key =
          ((unsigned long long)__float_as_uint(dq) << 32) | (unsigned)j;
      if (key < best) best = key;
    }
    red[threadIdx.x] = best;
    __syncthreads();
    for (int s = 128; s > 0; s >>= 1) {
      if (threadIdx.x < s && red[threadIdx.x + s] < red[threadIdx.x])
        red[threadIdx.x] = red[threadIdx.x + s];
      __syncthreads();
    }
    if (threadIdx.x == 0) atomicMin(&win[row], red[0]);
    __syncthreads();
  }
}

// ---------------- out: gather z_q, write indices, per-row loss (f64) ----------------
__global__ __launch_bounds__(256)
void vq_out(const float* __restrict__ z, const float* __restrict__ cb,
            const unsigned long long* __restrict__ win, float* __restrict__ out,
            double* __restrict__ loss64) {
  int wid = threadIdx.x >> 6, lane = threadIdx.x & 63;
  int row = blockIdx.x * 4 + wid;
  int I1 = (int)(win[row] & 8191ULL);
  const float* zp = z + (size_t)row * DIM + lane * 8;
  const float* cp = cb + (size_t)I1 * DIM + lane * 8;
  float4 z0 = *(const float4*)zp, z1 = *(const float4*)(zp + 4);
  float4 c0 = *(const float4*)cp, c1 = *(const float4*)(cp + 4);
  *(float4*)&out[(size_t)row * DIM + lane * 8] = c0;
  *(float4*)&out[(size_t)row * DIM + lane * 8 + 4] = c1;
  double s = 0.0, d;
  d = (double)z0.x - c0.x; s += d * d;
  d = (double)z0.y - c0.y; s += d * d;
  d = (double)z0.z - c0.z; s += d * d;
  d = (double)z0.w - c0.w; s += d * d;
  d = (double)z1.x - c1.x; s += d * d;
  d = (double)z1.y - c1.y; s += d * d;
  d = (double)z1.z - c1.z; s += d * d;
  d = (double)z1.w - c1.w; s += d * d;
#pragma unroll
  for (int m = 32; m >= 1; m >>= 1) s += __shfl_down(s, m, 64);
  if (lane == 0) {
    loss64[row] = s;
    out[(size_t)N_ROWS * DIM + row] = (float)I1;
  }
}

// ---------------- loss: deterministic reduction ----------------
__global__ __launch_bounds__(1024)
void vq_loss(const double* __restrict__ loss64, float* __restrict__ out) {
  __shared__ double sd[1024];
  double s = 0.0;
  for (int i = threadIdx.x; i < N_ROWS; i += 1024) s += loss64[i];
  sd[threadIdx.x] = s;
  __syncthreads();
  for (int k = 512; k > 0; k >>= 1) {
    if (threadIdx.x < k) sd[threadIdx.x] += sd[threadIdx.x + k];
    __syncthreads();
  }
  if (threadIdx.x == 0)
    out[(size_t)N_ROWS * DIM + N_ROWS] =
        (float)(BETA * sd[0] / ((double)N_ROWS * (double)DIM));
}

extern "C" void kernel_launch(void* const* d_in, const int* in_sizes, int n_in,
                              void* d_out, int out_size, void* d_ws, size_t ws_size,
                              hipStream_t stream) {
  const float* z = (const float*)d_in[0];
  const float* cb = (const float*)d_in[1];
  float* out = (float*)d_out;
  char* ws = (char*)d_ws;

  // fast-path ws layout
  const size_t OFF_ZH = 0;                         // 33,554,432
  const size_t OFF_CH = 33554432;                  //  8,388,608
  const size_t OFF_S1 = 41943040;                  //    131,072
  const size_t OFF_MT = 42074112;                  //    131,072
  const size_t OFF_WIN = 42205184;                 //    262,144
  const size_t OFF_L64 = 42467328;                 //    262,144
  const size_t OFF_TM = 42729472;                  //  8,388,608
  const size_t OFF_OC = 51118080;                  //         16
  const size_t OFF_OV = 51118096;                  // list...
  const size_t MIN_FAST = OFF_OV + (size_t)8 * 1024 * 1024;

  if (ws_size >= MIN_FAST) {
    u16* zh = (u16*)(ws + OFF_ZH);
    u16* ch = (u16*)(ws + OFF_CH);
    float* s1f = (float*)(ws + OFF_S1);
    float* mthr = (float*)(ws + OFF_MT);
    unsigned long long* win = (unsigned long long*)(ws + OFF_WIN);
    double* loss64 = (double*)(ws + OFF_L64);
    float* tilemax = (float*)(ws + OFF_TM);
    int* ovcnt = (int*)(ws + OFF_OC);
    uint2* ovlist = (uint2*)(ws + OFF_OV);
    long long gc = (long long)(ws_size - OFF_OV) / 8;
    if (gc > 6 * 1024 * 1024) gc = 6 * 1024 * 1024;
    int gcap = (int)gc;

    vq_cvt<<<N_ROWS * DIM / 8 / 256, 256, 0, stream>>>(z, zh, 1.0f,
                                                       N_ROWS * DIM / 8, ovcnt);
    vq_cvt<<<K_CODES * DIM / 8 / 256, 256, 0, stream>>>(cb, ch, 4096.0f,
                                                        K_CODES * DIM / 8, nullptr);
    vq_s1<<<N_ROWS / 256, 256, 0, stream>>>(z, s1f);
    vq_gemm<<<dim3((K_CODES / BN) * (N_ROWS / BM)), 512, 0, stream>>>(
        zh, ch, tilemax, ovlist, ovcnt, gcap);
    vq_merge<<<N_ROWS / 256, 256, 0, stream>>>(tilemax, mthr, win);
    vq_overflow<<<2048, 256, 0, stream>>>(z, cb, s1f, mthr, ovlist, ovcnt, gcap, win);
    vq_fallback<<<2048, 256, 0, stream>>>(z, cb, s1f, ovcnt, gcap, 0, win);
    vq_out<<<N_ROWS / 4, 256, 0, stream>>>(z, cb, win, out, loss64);
    vq_loss<<<1, 1024, 0, stream>>>(loss64, out);
  } else {
    // tiny-ws safe path: exact full scan
    float* s1f = (float*)(ws + 0);                                 // 131,072
    unsigned long long* win = (unsigned long long*)(ws + 131072);  // 262,144
    double* loss64 = (double*)(ws + 393216);                       // 262,144
    vq_s1<<<N_ROWS / 256, 256, 0, stream>>>(z, s1f);
    vq_init<<<N_ROWS / 256, 256, 0, stream>>>(win);
    vq_fallback<<<2048, 256, 0, stream>>>(z, cb, s1f, nullptr, 0, 1, win);
    vq_out<<<N_ROWS / 4, 256, 0, stream>>>(z, cb, win, out, loss64);
    vq_loss<<<1, 1024, 0, stream>>>(loss64, out);
  }
}

// Round 18
// 661.840 us; speedup vs baseline: 2.4312x; 1.0242x over previous
//
#include <hip/hip_runtime.h>
#include <cfloat>
#include <cstdint>
#include <cstddef>

#define N_ROWS 32768
#define K_CODES 8192
#define DIM 512
#define BETA 0.25

typedef unsigned short u16;
typedef _Float16 half8 __attribute__((ext_vector_type(8)));
typedef float f32x4 __attribute__((ext_vector_type(4)));

#define BM 256           // block rows (z)
#define BN 256           // block cols (codes)
#define SKH 32           // k-halves per ring sub-tile
#define NPH (DIM / SKH)  // 16 phases
#define OVCAP 512        // per-block LDS overflow buffer entries
#define DELTA_A 0.28f    // append window on scaled dot (safety bound needs 0.213)

#define GLOAD_LDS16(g, l)                                          \
  __builtin_amdgcn_global_load_lds(                                \
      (const __attribute__((address_space(1))) void*)(g),          \
      (__attribute__((address_space(3))) void*)(l), 16, 0, 0)

__device__ inline u16 f2h(float x) {
  union { _Float16 h; u16 u; } c;
  c.h = (_Float16)x;
  return c.u;
}

// ---------------- cvt: f32 -> f16 (optionally scaled), 8 elems/thread ----------------
__global__ __launch_bounds__(256)
void vq_cvt(const float* __restrict__ src, u16* __restrict__ dst, float scale,
            int n8, int* ovcnt_reset) {
  if (ovcnt_reset != nullptr && blockIdx.x == 0 && threadIdx.x == 0) *ovcnt_reset = 0;
  int i = blockIdx.x * 256 + threadIdx.x;
  if (i >= n8) return;
  float4 a = ((const float4*)src)[(size_t)i * 2];
  float4 b = ((const float4*)src)[(size_t)i * 2 + 1];
  uint4 o;
  o.x = (unsigned)f2h(a.x * scale) | ((unsigned)f2h(a.y * scale) << 16);
  o.y = (unsigned)f2h(a.z * scale) | ((unsigned)f2h(a.w * scale) << 16);
  o.z = (unsigned)f2h(b.x * scale) | ((unsigned)f2h(b.y * scale) << 16);
  o.w = (unsigned)f2h(b.z * scale) | ((unsigned)f2h(b.w * scale) << 16);
  ((uint4*)dst)[i] = o;
}

// ---------------- s1: numpy-exact fp32 pairwise sum of z*z (float4 loads) ------------
__global__ __launch_bounds__(256)
void vq_s1(const float* __restrict__ z, float* __restrict__ s1out) {
  int row = blockIdx.x * 256 + threadIdx.x;
  const float* p = z + (size_t)row * DIM;
  float lf[4];
#pragma unroll
  for (int L = 0; L < 4; ++L) {
    const float* q = p + L * 128;
    float4 a = *(const float4*)q;
    float4 b = *(const float4*)(q + 4);
    float r[8];
    r[0] = __fmul_rn(a.x, a.x); r[1] = __fmul_rn(a.y, a.y);
    r[2] = __fmul_rn(a.z, a.z); r[3] = __fmul_rn(a.w, a.w);
    r[4] = __fmul_rn(b.x, b.x); r[5] = __fmul_rn(b.y, b.y);
    r[6] = __fmul_rn(b.z, b.z); r[7] = __fmul_rn(b.w, b.w);
#pragma unroll
    for (int i = 8; i < 128; i += 8) {
      float4 c = *(const float4*)(q + i);
      float4 d = *(const float4*)(q + i + 4);
      r[0] = __fadd_rn(r[0], __fmul_rn(c.x, c.x));
      r[1] = __fadd_rn(r[1], __fmul_rn(c.y, c.y));
      r[2] = __fadd_rn(r[2], __fmul_rn(c.z, c.z));
      r[3] = __fadd_rn(r[3], __fmul_rn(c.w, c.w));
      r[4] = __fadd_rn(r[4], __fmul_rn(d.x, d.x));
      r[5] = __fadd_rn(r[5], __fmul_rn(d.y, d.y));
      r[6] = __fadd_rn(r[6], __fmul_rn(d.z, d.z));
      r[7] = __fadd_rn(r[7], __fmul_rn(d.w, d.w));
    }
    float s01 = __fadd_rn(r[0], r[1]);
    float s23 = __fadd_rn(r[2], r[3]);
    float s45 = __fadd_rn(r[4], r[5]);
    float s67 = __fadd_rn(r[6], r[7]);
    lf[L] = __fadd_rn(__fadd_rn(s01, s23), __fadd_rn(s45, s67));
  }
  s1out[row] = __fadd_rn(__fadd_rn(lf[0], lf[1]), __fadd_rn(lf[2], lf[3]));
}

// ---------------- gemm: r10/r17-validated 256x256 counted-vmcnt ring + XCD tiling ----
__global__ __launch_bounds__(512, 2)
void vq_gemm(const u16* __restrict__ zh, const u16* __restrict__ ch,
             float* __restrict__ tilemax, uint2* __restrict__ ovlist,
             int* __restrict__ ovcnt, int gcap) {
  __shared__ u16 ring[4][16384];  // per slot: A 8192 halves | B 8192 halves
  __shared__ float rmaxw[4][BM];
  __shared__ uint2 obuf[OVCAP];
  __shared__ int ocnt, gbase;
  const int tid = threadIdx.x;
  const int lane = tid & 63;
  const int wid = tid >> 6;  // 0..7
  const int wrow = (wid >> 2) * 128;
  const int wcol = (wid & 3) * 64;
  // XCD-aware swizzle: xcd = wg&7 owns colblocks 4*xcd..4*xcd+3; col-inner sweep.
  const int wg = blockIdx.x;
  const int xcd = wg & 7;
  const int kk = wg >> 3;               // 0..511
  const int colb = xcd * 4 + (kk & 3);  // 0..31
  const int rowb = kk >> 2;             // 0..127
  const int col0 = colb * BN;
  const int row0 = rowb * BM;
  if (tid == 0) ocnt = 0;

  f32x4 acc[8][4];
#pragma unroll
  for (int m = 0; m < 8; ++m)
#pragma unroll
    for (int n = 0; n < 4; ++n) acc[m][n] = (f32x4){0.f, 0.f, 0.f, 0.f};

  // stage addressing (linear LDS dest, pre-swizzled global source; rule #21)
  const int arow = tid >> 2;  // 0..127
  const int sslot8 = (((tid & 3) ^ ((tid >> 3) & 3))) * 8;
  const u16* pa0 = zh + (size_t)(row0 + arow) * DIM + sslot8;
  const u16* pa1 = pa0 + (size_t)128 * DIM;
  const u16* pb0 = ch + (size_t)(col0 + arow) * DIM + sslot8;
  const u16* pb1 = pb0 + (size_t)128 * DIM;
  const unsigned dof = tid * 8;  // halves

#define STAGE(s)                                              \
  {                                                           \
    u16* sl_ = ring[(s) & 3];                                 \
    GLOAD_LDS16(pa0 + (s) * SKH, sl_ + dof);                  \
    GLOAD_LDS16(pa1 + (s) * SKH, sl_ + 4096 + dof);           \
    GLOAD_LDS16(pb0 + (s) * SKH, sl_ + 8192 + dof);           \
    GLOAD_LDS16(pb1 + (s) * SKH, sl_ + 12288 + dof);          \
  }

  // ds_read byte offsets (swizzled; validated 0-conflict pattern)
  const int xorv = ((lane >> 4) ^ ((lane >> 1) & 3)) << 4;
  const int aoff = (wrow + (lane & 15)) * 64 + xorv;           // + m*1024
  const int boff = 16384 + (wcol + (lane & 15)) * 64 + xorv;   // + n*1024

  // prologue: stage sub-tiles 0 and 1 (8 loads in flight)
  STAGE(0);
  STAGE(1);

#pragma unroll
  for (int s = 0; s < NPH; ++s) {
    // 1. issue next prefetch (distance 2)
    if (s + 2 < NPH) STAGE(s + 2);
    // 2. counted wait: own sub-tile-s loads complete (8 newer may stay in flight)
    if (s < NPH - 2) {
      asm volatile("s_waitcnt vmcnt(8)" ::: "memory");
    } else if (s == NPH - 2) {
      asm volatile("s_waitcnt vmcnt(4)" ::: "memory");
    } else {
      asm volatile("s_waitcnt vmcnt(0)" ::: "memory");
    }
    __builtin_amdgcn_sched_barrier(0);
    // 3. all waves' sub-tile-s loads landed
    __builtin_amdgcn_s_barrier();
    // 4. fragment reads for this sub-tile
    const char* sl = (const char*)ring[s & 3];
    half8 af[8], bf[4];
#pragma unroll
    for (int m = 0; m < 8; ++m)
      af[m] = *(const half8*)(sl + aoff + m * 1024);
#pragma unroll
    for (int n = 0; n < 4; ++n)
      bf[n] = *(const half8*)(sl + boff + n * 1024);
    // 5. drain LDS reads; fence the scheduler (rule #18)
    asm volatile("s_waitcnt lgkmcnt(0)" ::: "memory");
    __builtin_amdgcn_sched_barrier(0);
    // 6. MFMA cluster (T5)
    __builtin_amdgcn_s_setprio(1);
#pragma unroll
    for (int m = 0; m < 8; ++m)
#pragma unroll
      for (int n = 0; n < 4; ++n)
        acc[m][n] = __builtin_amdgcn_mfma_f32_16x16x32_f16(af[m], bf[n],
                                                           acc[m][n], 0, 0, 0);
    __builtin_amdgcn_s_setprio(0);
  }
#undef STAGE

  // epilogue pass 1: per-row max over this wave's 64 cols -> rmaxw[wn]
  const int wn = wid & 3;
#pragma unroll
  for (int m = 0; m < 8; ++m) {
#pragma unroll
    for (int rg = 0; rg < 4; ++rg) {
      float mx = acc[m][0][rg];
#pragma unroll
      for (int n = 1; n < 4; ++n) mx = fmaxf(mx, acc[m][n][rg]);
#pragma unroll
      for (int s = 1; s <= 8; s <<= 1) mx = fmaxf(mx, __shfl_xor(mx, s, 64));
      int Rloc = wrow + m * 16 + (lane >> 4) * 4 + rg;
      if ((lane & 15) == 0) rmaxw[wn][Rloc] = mx;
    }
  }
  __syncthreads();
  // epilogue pass 2: combined 256-col tile max -> tilemax + threshold append (LDS buf)
#pragma unroll
  for (int m = 0; m < 8; ++m) {
#pragma unroll
    for (int rg = 0; rg < 4; ++rg) {
      int Rloc = wrow + m * 16 + (lane >> 4) * 4 + rg;
      int grow = row0 + Rloc;
      float gm = fmaxf(fmaxf(rmaxw[0][Rloc], rmaxw[1][Rloc]),
                       fmaxf(rmaxw[2][Rloc], rmaxw[3][Rloc]));
      if (wn == 0 && (lane & 15) == 0)
        tilemax[(size_t)colb * N_ROWS + grow] = gm;
      float thr = gm - DELTA_A;
#pragma unroll
      for (int n = 0; n < 4; ++n) {
        float v = acc[m][n][rg];
        if (v >= thr) {
          int code = col0 + wcol + n * 16 + (lane & 15);
          uint2 e = make_uint2(((unsigned)grow << 13) | (unsigned)code,
                               __float_as_uint(v));
          int p = atomicAdd(&ocnt, 1);
          if (p < OVCAP) obuf[p] = e;
          else {
            int g = atomicAdd(ovcnt, 1);
            if (g < gcap) ovlist[g] = e;
          }
        }
      }
    }
  }
  __syncthreads();
  int n = ocnt < OVCAP ? ocnt : OVCAP;
  if (tid == 0) gbase = atomicAdd(ovcnt, n);
  __syncthreads();
  for (int i = tid; i < n; i += 512) {
    int g = gbase + i;
    if (g < gcap) ovlist[g] = obuf[i];
  }
}

// ---------------- merge: per-row global max (8 ILP chains over 32 tiles) ------------
__global__ __launch_bounds__(256)
void vq_merge(const float* __restrict__ tilemax, float* __restrict__ mthr,
              unsigned long long* __restrict__ win) {
  int row = blockIdx.x * 256 + threadIdx.x;
  float g[8];
#pragma unroll
  for (int t = 0; t < 8; ++t) g[t] = tilemax[(size_t)t * N_ROWS + row];
#pragma unroll
  for (int tt = 1; tt < 4; ++tt)
#pragma unroll
    for (int t = 0; t < 8; ++t)
      g[t] = fmaxf(g[t], tilemax[(size_t)(tt * 8 + t) * N_ROWS + row]);
  float gg = fmaxf(fmaxf(fmaxf(g[0], g[1]), fmaxf(g[2], g[3])),
                   fmaxf(fmaxf(g[4], g[5]), fmaxf(g[6], g[7])));
  mthr[row] = gg - DELTA_A;
  win[row] = ~0ULL;
}

__global__ __launch_bounds__(256)
void vq_init(unsigned long long* __restrict__ win) {
  int row = blockIdx.x * 256 + threadIdx.x;
  win[row] = ~0ULL;
}

// ---------------- overflow: filter + exact fp32 chain re-rank ----------------
__global__ __launch_bounds__(256)
void vq_overflow(const float* __restrict__ z, const float* __restrict__ cb,
                 const float* __restrict__ s1, const float* __restrict__ mthr,
                 const uint2* __restrict__ ovlist, const int* __restrict__ ovcnt,
                 int gcap, unsigned long long* __restrict__ win) {
  int n = *ovcnt;
  if (n > gcap) n = gcap;
  for (int i = blockIdx.x * 256 + threadIdx.x; i < n; i += gridDim.x * 256) {
    uint2 e = ovlist[i];
    int row = e.x >> 13;
    int code = e.x & 8191;
    if (__uint_as_float(e.y) < mthr[row]) continue;
    const float* zp = z + (size_t)row * DIM;
    const float* cp = cb + (size_t)code * DIM;
    float acc = 0.f;
    for (int k = 0; k < DIM; k += 4) {
      float4 zv = *(const float4*)(zp + k);
      float4 cv = *(const float4*)(cp + k);
      acc = fmaf(zv.x, cv.x, acc);
      acc = fmaf(zv.y, cv.y, acc);
      acc = fmaf(zv.z, cv.z, acc);
      acc = fmaf(zv.w, cv.w, acc);
    }
    float dq = __fsub_rn(s1[row], __fmul_rn(2.0f, acc));
    unsigned long long key =
        ((unsigned long long)__float_as_uint(dq) << 32) | (unsigned)code;
    atomicMin(&win[row], key);
  }
}

// ---------------- fallback: gated full exact scan (overflow safety) ----------------
__global__ __launch_bounds__(256)
void vq_fallback(const float* __restrict__ z, const float* __restrict__ cb,
                 const float* __restrict__ s1, const int* __restrict__ ovcnt,
                 int gcap, int force, unsigned long long* __restrict__ win) {
  if (!force && *ovcnt <= gcap) return;
  __shared__ float zrow[DIM];
  __shared__ unsigned long long red[256];
  for (int row = blockIdx.x; row < N_ROWS; row += gridDim.x) {
    __syncthreads();
    for (int t = threadIdx.x; t < DIM; t += 256) zrow[t] = z[(size_t)row * DIM + t];
    __syncthreads();
    float s1v = s1[row];
    unsigned long long best = ~0ULL;
    for (int j = threadIdx.x; j < K_CODES; j += 256) {
      const float* cp = cb + (size_t)j * DIM;
      float acc = 0.f;
      for (int k = 0; k < DIM; ++k) acc = fmaf(zrow[k], cp[k], acc);
      float dq = __fsub_rn(s1v, __fmul_rn(2.0f, acc));
      unsigned long long key =
          ((unsigned long long)__float_as_uint(dq) << 32) | (unsigned)j;
      if (key < best) best = key;
    }
    red[threadIdx.x] = best;
    __syncthreads();
    for (int s = 128; s > 0; s >>= 1) {
      if (threadIdx.x < s && red[threadIdx.x + s] < red[threadIdx.x])
        red[threadIdx.x] = red[threadIdx.x + s];
      __syncthreads();
    }
    if (threadIdx.x == 0) atomicMin(&win[row], red[0]);
    __syncthreads();
  }
}

// ---------------- out: gather z_q, write indices, per-row loss (f64) ----------------
__global__ __launch_bounds__(256)
void vq_out(const float* __restrict__ z, const float* __restrict__ cb,
            const unsigned long long* __restrict__ win, float* __restrict__ out,
            double* __restrict__ loss64) {
  int wid = threadIdx.x >> 6, lane = threadIdx.x & 63;
  int row = blockIdx.x * 4 + wid;
  int I1 = (int)(win[row] & 8191ULL);
  const float* zp = z + (size_t)row * DIM + lane * 8;
  const float* cp = cb + (size_t)I1 * DIM + lane * 8;
  float4 z0 = *(const float4*)zp, z1 = *(const float4*)(zp + 4);
  float4 c0 = *(const float4*)cp, c1 = *(const float4*)(cp + 4);
  *(float4*)&out[(size_t)row * DIM + lane * 8] = c0;
  *(float4*)&out[(size_t)row * DIM + lane * 8 + 4] = c1;
  double s = 0.0, d;
  d = (double)z0.x - c0.x; s += d * d;
  d = (double)z0.y - c0.y; s += d * d;
  d = (double)z0.z - c0.z; s += d * d;
  d = (double)z0.w - c0.w; s += d * d;
  d = (double)z1.x - c1.x; s += d * d;
  d = (double)z1.y - c1.y; s += d * d;
  d = (double)z1.z - c1.z; s += d * d;
  d = (double)z1.w - c1.w; s += d * d;
#pragma unroll
  for (int m = 32; m >= 1; m >>= 1) s += __shfl_down(s, m, 64);
  if (lane == 0) {
    loss64[row] = s;
    out[(size_t)N_ROWS * DIM + row] = (float)I1;
  }
}

// ---------------- loss: deterministic reduction ----------------
__global__ __launch_bounds__(1024)
void vq_loss(const double* __restrict__ loss64, float* __restrict__ out) {
  __shared__ double sd[1024];
  double s = 0.0;
  for (int i = threadIdx.x; i < N_ROWS; i += 1024) s += loss64[i];
  sd[threadIdx.x] = s;
  __syncthreads();
  for (int k = 512; k > 0; k >>= 1) {
    if (threadIdx.x < k) sd[threadIdx.x] += sd[threadIdx.x + k];
    __syncthreads();
  }
  if (threadIdx.x == 0)
    out[(size_t)N_ROWS * DIM + N_ROWS] =
        (float)(BETA * sd[0] / ((double)N_ROWS * (double)DIM));
}

extern "C" void kernel_launch(void* const* d_in, const int* in_sizes, int n_in,
                              void* d_out, int out_size, void* d_ws, size_t ws_size,
                              hipStream_t stream) {
  const float* z = (const float*)d_in[0];
  const float* cb = (const float*)d_in[1];
  float* out = (float*)d_out;
  char* ws = (char*)d_ws;

  // fast-path ws layout
  const size_t OFF_ZH = 0;                         // 33,554,432
  const size_t OFF_CH = 33554432;                  //  8,388,608
  const size_t OFF_S1 = 41943040;                  //    131,072
  const size_t OFF_MT = 42074112;                  //    131,072
  const size_t OFF_WIN = 42205184;                 //    262,144
  const size_t OFF_L64 = 42467328;                 //    262,144
  const size_t OFF_TM = 42729472;                  //  8,388,608
  const size_t OFF_OC = 51118080;                  //         16
  const size_t OFF_OV = 51118096;                  // list...
  const size_t MIN_FAST = OFF_OV + (size_t)8 * 1024 * 1024;

  if (ws_size >= MIN_FAST) {
    u16* zh = (u16*)(ws + OFF_ZH);
    u16* ch = (u16*)(ws + OFF_CH);
    float* s1f = (float*)(ws + OFF_S1);
    float* mthr = (float*)(ws + OFF_MT);
    unsigned long long* win = (unsigned long long*)(ws + OFF_WIN);
    double* loss64 = (double*)(ws + OFF_L64);
    float* tilemax = (float*)(ws + OFF_TM);
    int* ovcnt = (int*)(ws + OFF_OC);
    uint2* ovlist = (uint2*)(ws + OFF_OV);
    long long gc = (long long)(ws_size - OFF_OV) / 8;
    if (gc > 6 * 1024 * 1024) gc = 6 * 1024 * 1024;
    int gcap = (int)gc;

    vq_cvt<<<N_ROWS * DIM / 8 / 256, 256, 0, stream>>>(z, zh, 1.0f,
                                                       N_ROWS * DIM / 8, ovcnt);
    vq_cvt<<<K_CODES * DIM / 8 / 256, 256, 0, stream>>>(cb, ch, 4096.0f,
                                                        K_CODES * DIM / 8, nullptr);
    vq_s1<<<N_ROWS / 256, 256, 0, stream>>>(z, s1f);
    vq_gemm<<<dim3((K_CODES / BN) * (N_ROWS / BM)), 512, 0, stream>>>(
        zh, ch, tilemax, ovlist, ovcnt, gcap);
    vq_merge<<<N_ROWS / 256, 256, 0, stream>>>(tilemax, mthr, win);
    vq_overflow<<<2048, 256, 0, stream>>>(z, cb, s1f, mthr, ovlist, ovcnt, gcap, win);
    vq_fallback<<<2048, 256, 0, stream>>>(z, cb, s1f, ovcnt, gcap, 0, win);
    vq_out<<<N_ROWS / 4, 256, 0, stream>>>(z, cb, win, out, loss64);
    vq_loss<<<1, 1024, 0, stream>>>(loss64, out);
  } else {
    // tiny-ws safe path: exact full scan
    float* s1f = (float*)(ws + 0);                                 // 131,072
    unsigned long long* win = (unsigned long long*)(ws + 131072);  // 262,144
    double* loss64 = (double*)(ws + 393216);                       // 262,144
    vq_s1<<<N_ROWS / 256, 256, 0, stream>>>(z, s1f);
    vq_init<<<N_ROWS / 256, 256, 0, stream>>>(win);
    vq_fallback<<<2048, 256, 0, stream>>>(z, cb, s1f, nullptr, 0, 1, win);
    vq_out<<<N_ROWS / 4, 256, 0, stream>>>(z, cb, win, out, loss64);
    vq_loss<<<1, 1024, 0, stream>>>(loss64, out);
  }
}